// Round 9
// baseline (124.425 us; speedup 1.0000x reference)
//
#include <hip/hip_runtime.h>
#include <hip/hip_bf16.h>

// Problem constants
#define K_DIM 4096
#define N_DIM 14336
#define M_DIM 256
#define BM 128
#define BN 64
#define BK 128          // one quant group per iteration
#define NITER 32        // K_DIM / BK
#define FRS 136         // W row stride in shorts (BK + 8 pad)

typedef __attribute__((ext_vector_type(4))) float f32x4;
typedef __attribute__((ext_vector_type(8))) short short8;

__device__ __forceinline__ unsigned short f2bf(float f) {
    union { float f; unsigned u; } v; v.f = f;
    unsigned r = v.u + 0x7fffu + ((v.u >> 16) & 1u);   // RNE
    return (unsigned short)(r >> 16);
}

// x (fp32 [256][4096]) -> bf16 MFMA-A-fragment order. chunk = ktile*16+mtile;
// lane l of chunk holds x[mtile*16+(l&15)][ktile*32+(l>>4)*8 ..+8] (1 KB/chunk)
__global__ void convert_x_kernel(const float* __restrict__ x,
                                 unsigned short* __restrict__ xf) {
    int t = blockIdx.x * blockDim.x + threadIdx.x;   // 0..131071
    int chunk = t >> 6;
    int lane  = t & 63;
    int ktile = chunk >> 4;
    int mtile = chunk & 15;
    int m = mtile * 16 + (lane & 15);
    int k = ktile * 32 + ((lane >> 4) << 3);
    const float* xp = x + (size_t)m * K_DIM + k;
    float4 lo = *(const float4*)xp;
    float4 hi = *(const float4*)(xp + 4);
    union { unsigned short s[8]; int4 v; } o;
    o.s[0] = f2bf(lo.x); o.s[1] = f2bf(lo.y); o.s[2] = f2bf(lo.z); o.s[3] = f2bf(lo.w);
    o.s[4] = f2bf(hi.x); o.s[5] = f2bf(hi.y); o.s[6] = f2bf(hi.z); o.s[7] = f2bf(hi.w);
    *(int4*)(xf + ((size_t)t << 3)) = o.v;
}

// v11: r1 skeleton (proven 93.5us) + 448 blocks + bf16-A double-set + cheap
// dequant. 512 thr = 8 waves (4m x 2n), BM=128 x BN=64, BK=128 (=1 group).
// Per phase per block ~40 KB of independent register/LDS-bound loads in
// flight (MLP >> glds designs). Plain __syncthreads; all loads consumed
// in their issue phase, so the vmcnt drain at the barrier costs ~nothing.
__global__ __launch_bounds__(512, 2)
void plq_gemm_v11(const unsigned short* __restrict__ xf,
                  const int* __restrict__ q,
                  const float* __restrict__ qs,
                  const float* __restrict__ qb,
                  const float* __restrict__ bias,
                  float* __restrict__ out)
{
    __shared__ unsigned short wlds[2][BN * FRS];   // 34.8 KB dequantized W

    const int tid  = threadIdx.x;
    const int lane = tid & 63;
    const int wv   = tid >> 6;          // 0..7
    const int wm   = wv >> 1;           // 0..3 : rows wm*32..+32
    const int wn   = wv & 1;            // 0..1 : cols wn*32..+32
    const int l4   = lane >> 4;
    const int lc   = lane & 15;

    // XCD-chunked remap (448 = 8*56): m-half twins adjacent on one XCD
    const int gid = (blockIdx.x & 7) * 56 + (blockIdx.x >> 3);
    const int mh  = gid & 1;
    const int n0  = (gid >> 1) * BN;

    // q staging role: 2 cols (nl, nl+1) x 8 consecutive k at kl
    const int nl = (tid & 31) * 2;
    const int kl = (tid >> 5) * 8;

    f32x4 acc[2][2] = {};
    short8 afX[4][2], afY[4][2];        // [kstep][mfrag] static double set
    int2   qr[8];
    float2 sv, zv;

    auto loadQ = [&](int i) {           // 8 int2 + 2 scalars, all independent
        const int* qp = q + (size_t)(i * BK + kl) * N_DIM + (n0 + nl);
        #pragma unroll
        for (int j = 0; j < 8; ++j) qr[j] = *(const int2*)(qp + (size_t)j * N_DIM);
        sv = *(const float2*)(qs + (size_t)i * N_DIM + (n0 + nl));
        zv = *(const float2*)(qb + (size_t)i * N_DIM + (n0 + nl));
    };
    auto loadAf = [&](int i, short8 (&af)[4][2]) {   // 8 x 16B from L2-hot xf
        #pragma unroll
        for (int ks = 0; ks < 4; ++ks)
            #pragma unroll
            for (int mf = 0; mf < 2; ++mf) {
                const int chunk = (i * 4 + ks) * 16 + (mh * 8 + wm * 2 + mf);
                af[ks][mf] = *(const short8*)(xf + ((size_t)chunk << 9) + (lane << 3));
            }
    };
    auto deq = [&](int b) {             // w = q*s+z, bf16-trunc pack via perm
        union { unsigned u[4]; int4 v; } p0, p1;
        #pragma unroll
        for (int j = 0; j < 4; ++j) {
            union { float f; unsigned w; } a0, a1, c0, c1;
            a0.f = (float)qr[2*j].x   * sv.x + zv.x;
            a1.f = (float)qr[2*j+1].x * sv.x + zv.x;
            c0.f = (float)qr[2*j].y   * sv.y + zv.y;
            c1.f = (float)qr[2*j+1].y * sv.y + zv.y;
            p0.u[j] = __builtin_amdgcn_perm(a1.w, a0.w, 0x07060302u);
            p1.u[j] = __builtin_amdgcn_perm(c1.w, c0.w, 0x07060302u);
        }
        *(int4*)&wlds[b][(nl + 0) * FRS + kl] = p0.v;
        *(int4*)&wlds[b][(nl + 1) * FRS + kl] = p1.v;
    };
    auto compute = [&](const short8 (&af)[4][2], int cur) {  // 8 b128 + 16 MFMA
        #pragma unroll
        for (int ks = 0; ks < 4; ++ks) {
            const int kb = ks * 32 + l4 * 8;
            short8 b0 = *(const short8*)&wlds[cur][(wn * 32 +      lc) * FRS + kb];
            short8 b1 = *(const short8*)&wlds[cur][(wn * 32 + 16 + lc) * FRS + kb];
            acc[0][0] = __builtin_amdgcn_mfma_f32_16x16x32_bf16(af[ks][0], b0, acc[0][0], 0, 0, 0);
            acc[0][1] = __builtin_amdgcn_mfma_f32_16x16x32_bf16(af[ks][0], b1, acc[0][1], 0, 0, 0);
            acc[1][0] = __builtin_amdgcn_mfma_f32_16x16x32_bf16(af[ks][1], b0, acc[1][0], 0, 0, 0);
            acc[1][1] = __builtin_amdgcn_mfma_f32_16x16x32_bf16(af[ks][1], b1, acc[1][1], 0, 0, 0);
        }
    };

    // ---- prologue: tile 0 ----
    loadQ(0);
    loadAf(0, afX);
    deq(0);
    __syncthreads();

    // ---- main loop: 16 x 2 phases (static afX/afY rotation) ----
    #pragma unroll 1
    for (int ii = 0; ii < 16; ++ii) {
        const int i = ii << 1;

        // even: compute(i) from wlds0+afX; stage i+1 (q->regs, A->afY)
        if (i + 1 < NITER) { loadQ(i + 1); loadAf(i + 1, afY); }
        compute(afX, 0);
        if (i + 1 < NITER) deq(1);
        __syncthreads();

        // odd: compute(i+1) from wlds1+afY; stage i+2 into afX
        if (i + 2 < NITER) { loadQ(i + 2); loadAf(i + 2, afX); }
        compute(afY, 1);
        if (i + 2 < NITER) deq(0);
        __syncthreads();
    }

    // ---- epilogue: C/D col = lane&15, row = (lane>>4)*4 + r ----
    #pragma unroll
    for (int nf = 0; nf < 2; ++nf) {
        const int n = n0 + wn * 32 + nf * 16 + lc;
        const float bv = bias[n];
        #pragma unroll
        for (int mf = 0; mf < 2; ++mf) {
            const int m0 = mh * BM + wm * 32 + mf * 16 + l4 * 4;
            #pragma unroll
            for (int r = 0; r < 4; ++r)
                out[(size_t)(m0 + r) * N_DIM + n] = acc[mf][nf][r] + bv;
        }
    }
}

// ---------------- fallback (no workspace): round-1 structure ----
#define FBN 64
#define FBK 128
#define FNITER 32
__global__ __launch_bounds__(512, 2)
void plq_gemm_fb(const float* __restrict__ x,
                 const int* __restrict__ q,
                 const float* __restrict__ qs,
                 const float* __restrict__ qb,
                 const float* __restrict__ bias,
                 float* __restrict__ out)
{
    __shared__ unsigned short wlds[2][FBN * FRS];
    const int tid  = threadIdx.x;
    const int lane = tid & 63;
    const int wv   = tid >> 6;
    const int wm   = wv >> 1;
    const int wn   = wv & 1;
    const int n0   = blockIdx.x * FBN;
    const int nl = (tid & 31) * 2;
    const int kl = (tid >> 5) * 8;

    f32x4 acc[4][2] = {};
    int2   qr[8];
    float2 sv, zv;

    auto loadq = [&](int i) {
        const int* qp = q + (size_t)(i * FBK + kl) * N_DIM + (n0 + nl);
        #pragma unroll
        for (int j = 0; j < 8; ++j) qr[j] = *(const int2*)(qp + (size_t)j * N_DIM);
        sv = *(const float2*)(qs + (size_t)i * N_DIM + (n0 + nl));
        zv = *(const float2*)(qb + (size_t)i * N_DIM + (n0 + nl));
    };
    auto deqw = [&](int b) {
        union { unsigned u[4]; int4 v; } p0, p1;
        #pragma unroll
        for (int j = 0; j < 4; ++j) {
            float a0 = (float)qr[2*j].x   * sv.x + zv.x;
            float a1 = (float)qr[2*j+1].x * sv.x + zv.x;
            float c0 = (float)qr[2*j].y   * sv.y + zv.y;
            float c1 = (float)qr[2*j+1].y * sv.y + zv.y;
            p0.u[j] = (unsigned)f2bf(a0) | ((unsigned)f2bf(a1) << 16);
            p1.u[j] = (unsigned)f2bf(c0) | ((unsigned)f2bf(c1) << 16);
        }
        *(int4*)&wlds[b][(nl + 0) * FRS + kl] = p0.v;
        *(int4*)&wlds[b][(nl + 1) * FRS + kl] = p1.v;
    };
    auto compute = [&](int i, int cur) {
        short8 afr[4][4];
        #pragma unroll
        for (int ks = 0; ks < 4; ++ks)
            #pragma unroll
            for (int mf = 0; mf < 4; ++mf) {
                int m = wm * 64 + mf * 16 + (lane & 15);
                int k = i * FBK + ks * 32 + ((lane >> 4) << 3);
                const float* xp = x + (size_t)m * K_DIM + k;
                float4 lo = *(const float4*)xp;
                float4 hi = *(const float4*)(xp + 4);
                union { unsigned short s[8]; short8 v; } u;
                u.s[0] = f2bf(lo.x); u.s[1] = f2bf(lo.y); u.s[2] = f2bf(lo.z); u.s[3] = f2bf(lo.w);
                u.s[4] = f2bf(hi.x); u.s[5] = f2bf(hi.y); u.s[6] = f2bf(hi.z); u.s[7] = f2bf(hi.w);
                afr[ks][mf] = u.v;
            }
        #pragma unroll
        for (int ks = 0; ks < 4; ++ks) {
            const int kb = ks * 32 + ((lane >> 4) << 3);
            short8 b0 = *(const short8*)&wlds[cur][(wn * 32 +      (lane & 15)) * FRS + kb];
            short8 b1 = *(const short8*)&wlds[cur][(wn * 32 + 16 + (lane & 15)) * FRS + kb];
            #pragma unroll
            for (int mf = 0; mf < 4; ++mf) {
                acc[mf][0] = __builtin_amdgcn_mfma_f32_16x16x32_bf16(afr[ks][mf], b0, acc[mf][0], 0, 0, 0);
                acc[mf][1] = __builtin_amdgcn_mfma_f32_16x16x32_bf16(afr[ks][mf], b1, acc[mf][1], 0, 0, 0);
            }
        }
    };

    loadq(0); deqw(0); __syncthreads();
    for (int i = 0; i < FNITER; ++i) {
        const int cur = i & 1;
        if (i + 1 < FNITER) loadq(i + 1);
        compute(i, cur);
        if (i + 1 < FNITER) deqw(cur ^ 1);
        __syncthreads();
    }
    #pragma unroll
    for (int nf = 0; nf < 2; ++nf) {
        const int n = n0 + wn * 32 + nf * 16 + (lane & 15);
        const float bb = bias[n];
        #pragma unroll
        for (int mf = 0; mf < 4; ++mf) {
            const int m0 = wm * 64 + mf * 16 + ((lane >> 4) << 2);
            #pragma unroll
            for (int r = 0; r < 4; ++r)
                out[(size_t)(m0 + r) * N_DIM + n] = acc[mf][nf][r] + bb;
        }
    }
}

extern "C" void kernel_launch(void* const* d_in, const int* in_sizes, int n_in,
                              void* d_out, int out_size, void* d_ws, size_t ws_size,
                              hipStream_t stream) {
    const float* x    = (const float*)d_in[0];
    const int*   qk   = (const int*)d_in[1];
    const float* qs   = (const float*)d_in[2];
    const float* qb   = (const float*)d_in[3];
    const float* bias = (const float*)d_in[4];
    float* out = (float*)d_out;

    const size_t xf_bytes = (size_t)M_DIM * K_DIM * sizeof(unsigned short);   // 2 MB
    if (ws_size >= xf_bytes) {
        unsigned short* xf = (unsigned short*)d_ws;
        convert_x_kernel<<<512, 256, 0, stream>>>(x, xf);
        const int grid = (M_DIM / BM) * (N_DIM / BN);   // 2 * 224 = 448
        plq_gemm_v11<<<grid, 512, 0, stream>>>(xf, qk, qs, qb, bias, out);
    } else {
        plq_gemm_fb<<<N_DIM / FBN, 512, 0, stream>>>(x, qk, qs, qb, bias, out);
    }
}